// Round 4
// baseline (308.367 us; speedup 1.0000x reference)
//
#include <hip/hip_runtime.h>
#include <math.h>

// FlashDiffAttention on MI355X (gfx950). Round 4: producer/consumer waves.
// Prep: K -> kws [bh][t][attn2][dc16][key32][8] bf16 ; V -> vws
// [bh][t][kc4][n256][8k] bf16 (DMA-linear, conflict-free frag reads).
// Main: 256 blocks (16 bh x 16 pairs), 512 thr = 8 waves:
//   waves 0..3 = QK/softmax (u=attn, mh=32-row group)  [producer]
//   waves 4..7 = PV         (nq = 64-wide n-quarter)   [consumer, lags 1 tile]
// One barrier per tile; K/V/sP/alpha double-buffered; per-block qt-pairing
// (31-g, g) -> exactly 66 tiles per block, exactly 1 block per CU.

#define S_LEN 2048
#define ROWSTR 2048
#define NEG_BIG (-3.0e38f)
#define QSCALE (1.44269504088896f * 0.0883883476483184f)  // log2(e)/sqrt(128)
#define LAMBDA_INIT 0.783605766532f

typedef __attribute__((ext_vector_type(8))) short short8;
typedef __attribute__((ext_vector_type(4))) float f32x4;

__device__ __forceinline__ short f2bf(float f) {
    unsigned u = __builtin_bit_cast(unsigned, f);
    u += 0x7fffu + ((u >> 16) & 1u);
    return (short)(u >> 16);
}

__device__ __forceinline__ void async16(const short* g, short* l) {
    __builtin_amdgcn_global_load_lds(
        (const __attribute__((address_space(1))) unsigned int*)g,
        (__attribute__((address_space(3))) unsigned int*)l, 16, 0, 0);
}

// ---------------- prepass ----------------
__global__ __launch_bounds__(256)
void prep_kernel(const float* __restrict__ k, const float* __restrict__ v,
                 short* __restrict__ kws, short* __restrict__ vws) {
    const int tid = threadIdx.x;
    const int bh  = blockIdx.x >> 6;
    const int t   = blockIdx.x & 63;
    const int b   = bh >> 3;
    const int h   = bh & 7;

    // K: thread = attn(2) x key(32) x dg(4); kws[attn][dc][key][8]
    {
        const int attn = tid >> 7;
        const int key  = (tid >> 2) & 31;
        const int dg   = tid & 3;
        const float* src = k + ((size_t)(b * S_LEN + t * 32 + key) * 16 + 2 * h + attn) * 128 + dg * 32;
        short* dstb = kws + ((size_t)(bh * 64 + t) << 13) + attn * 4096 + key * 8;
        #pragma unroll
        for (int i = 0; i < 4; ++i) {
            const float4 a0 = *(const float4*)(src + i * 8);
            const float4 a1 = *(const float4*)(src + i * 8 + 4);
            short8 sv;
            sv[0]=f2bf(a0.x); sv[1]=f2bf(a0.y); sv[2]=f2bf(a0.z); sv[3]=f2bf(a0.w);
            sv[4]=f2bf(a1.x); sv[5]=f2bf(a1.y); sv[6]=f2bf(a1.z); sv[7]=f2bf(a1.w);
            *(short8*)(dstb + (dg * 4 + i) * 256) = sv;
        }
    }
    // V: thread = n(256); vws[kc][n][8keys]
    {
        const int n = tid;
        const float* vsrc = v + ((size_t)(b * S_LEN + t * 32) * 16 + 2 * h + (n >> 7)) * 128 + (n & 127);
        short vv[32];
        #pragma unroll
        for (int key = 0; key < 32; ++key)
            vv[key] = f2bf(vsrc[(size_t)key * ROWSTR]);
        short* vdst = vws + ((size_t)(bh * 64 + t) << 13) + n * 8;
        #pragma unroll
        for (int kc = 0; kc < 4; ++kc)
            *(short8*)(vdst + kc * 2048) = *(short8*)&vv[kc * 8];
    }
}

// ---------------- main ----------------
__global__ __launch_bounds__(512, 2)
void fda_kernel(const short* __restrict__ kws, const short* __restrict__ vws,
                const float* __restrict__ q,
                const float* __restrict__ lq1, const float* __restrict__ lk1,
                const float* __restrict__ lq2, const float* __restrict__ lk2,
                float* __restrict__ out) {
    __shared__ short sK[2][8192];         // [buf][attn][dc16][key32][8]
    __shared__ short sV[2][8192];         // [buf][kc4][n256][8]
    __shared__ short sP[2][2][64][40];    // [buf][attn][row][key(+pad)]
    __shared__ float sAl[2][2][2];        // [buf][attn][mh]
    __shared__ float sL[2][64];           // [attn][row]
    __shared__ float sRed[4][64];         // [nq][row]

    const int tid  = threadIdx.x;
    const int w    = tid >> 6;
    const int lane = tid & 63;
    const int mi   = lane & 15;
    const int quad = lane >> 4;

    const int bh = blockIdx.x & 15;
    const int g  = blockIdx.x >> 4;       // 0..15
    const int b  = bh >> 3;
    const int h  = bh & 7;

    const bool isQK = (w < 4);
    const int u  = w & 1;                 // QK: attn
    const int mh = (w >> 1) & 1;          // QK: 32-row group
    const int nq = w - 4;                 // PV: n-quarter

    const short* ktile0 = kws + ((size_t)(bh * 64) << 13);
    const short* vtile0 = vws + ((size_t)(bh * 64) << 13);

    // lambda_full (all waves)
    float d1 = lq1[lane] * lk1[lane] + lq1[lane + 64] * lk1[lane + 64];
    float d2 = lq2[lane] * lk2[lane] + lq2[lane + 64] * lk2[lane + 64];
    #pragma unroll
    for (int off = 32; off; off >>= 1) {
        d1 += __shfl_xor(d1, off);
        d2 += __shfl_xor(d2, off);
    }
    const float lambda_full = expf(d1) - expf(d2) + LAMBDA_INIT;

    for (int ph = 0; ph < 2; ++ph) {
        const int qt = ph ? g : (31 - g);
        const int qbase = qt * 64;
        const int nt = 2 * qt + 2;

        // ---- per-phase state + tile-0 priming ----
        short8 qf[2][4];
        float mold = -1e30f;
        float lsum[2][4] = {{0.f,0.f,0.f,0.f},{0.f,0.f,0.f,0.f}};
        f32x4 O[2][4][4];

        if (isQK) {
            // stage K0 (this wave's 4KB half)
            const short* src = ktile0 + u * 4096 + mh * 2048 + lane * 8;
            short* dst = &sK[0][u * 4096 + mh * 2048 + lane * 8];
            #pragma unroll
            for (int c = 0; c < 4; ++c) async16(src + c * 512, dst + c * 512);
            // load Q fragments (rows mh*32 + m*16 + mi, attn u)
            #pragma unroll
            for (int m = 0; m < 2; ++m) {
                const float* p0 = q + ((size_t)(b * S_LEN + qbase + mh * 32 + m * 16 + mi) * 16 + 2 * h + u) * 128 + quad * 8;
                #pragma unroll
                for (int db = 0; db < 4; ++db) {
                    const float* p = p0 + db * 32;
                    const float4 a0 = *(const float4*)p;
                    const float4 a1 = *(const float4*)(p + 4);
                    short8 f;
                    f[0]=f2bf(a0.x*QSCALE); f[1]=f2bf(a0.y*QSCALE);
                    f[2]=f2bf(a0.z*QSCALE); f[3]=f2bf(a0.w*QSCALE);
                    f[4]=f2bf(a1.x*QSCALE); f[5]=f2bf(a1.y*QSCALE);
                    f[6]=f2bf(a1.z*QSCALE); f[7]=f2bf(a1.w*QSCALE);
                    qf[m][db] = f;
                }
            }
        } else {
            // stage V0 (this wave's slices)
            const short* src = vtile0 + nq * 512 + lane * 8;
            short* dst = &sV[0][nq * 512 + lane * 8];
            #pragma unroll
            for (int kc = 0; kc < 4; ++kc) async16(src + kc * 2048, dst + kc * 2048);
            #pragma unroll
            for (int a = 0; a < 2; ++a)
                #pragma unroll
                for (int m = 0; m < 4; ++m)
                    #pragma unroll
                    for (int nb = 0; nb < 4; ++nb)
                        O[a][m][nb] = (f32x4){0.f, 0.f, 0.f, 0.f};
        }
        __syncthreads();

        for (int t = 0; t < nt; ++t) {
            const int buf = t & 1;
            if (isQK) {
                // ---- QK(t) ----
                f32x4 S[2][2];
                #pragma unroll
                for (int m = 0; m < 2; ++m)
                    #pragma unroll
                    for (int kh = 0; kh < 2; ++kh)
                        S[m][kh] = (f32x4){0.f, 0.f, 0.f, 0.f};
                const short* kb = &sK[buf][u * 4096];
                #pragma unroll
                for (int db = 0; db < 4; ++db) {
                    #pragma unroll
                    for (int kh = 0; kh < 2; ++kh) {
                        const short8 kf = *(const short8*)(kb + (db * 4 + quad) * 256 + (kh * 16 + mi) * 8);
                        S[0][kh] = __builtin_amdgcn_mfma_f32_16x16x32_bf16(qf[0][db], kf, S[0][kh], 0, 0, 0);
                        S[1][kh] = __builtin_amdgcn_mfma_f32_16x16x32_bf16(qf[1][db], kf, S[1][kh], 0, 0, 0);
                    }
                }
                // prefetch K(t+1)
                if (t + 1 < nt) {
                    const short* src = ktile0 + ((size_t)(t + 1) << 13) + u * 4096 + mh * 2048 + lane * 8;
                    short* dst = &sK[buf ^ 1][u * 4096 + mh * 2048 + lane * 8];
                    #pragma unroll
                    for (int c = 0; c < 4; ++c) async16(src + c * 512, dst + c * 512);
                }
                // causal mask (near-diagonal tiles only)
                if (t >= 2 * qt + mh) {
                    const int r0 = qbase + mh * 32;
                    #pragma unroll
                    for (int m = 0; m < 2; ++m)
                        #pragma unroll
                        for (int kh = 0; kh < 2; ++kh)
                            #pragma unroll
                            for (int r = 0; r < 4; ++r)
                                if (t * 32 + kh * 16 + mi > r0 + m * 16 + quad * 4 + r)
                                    S[m][kh][r] = NEG_BIG;
                }
                // wave tile-max (shared over this wave's 32 rows)
                float mx = NEG_BIG;
                #pragma unroll
                for (int m = 0; m < 2; ++m)
                    #pragma unroll
                    for (int kh = 0; kh < 2; ++kh)
                        mx = fmaxf(mx, fmaxf(fmaxf(S[m][kh][0], S[m][kh][1]),
                                             fmaxf(S[m][kh][2], S[m][kh][3])));
                #pragma unroll
                for (int off = 32; off; off >>= 1)
                    mx = fmaxf(mx, __shfl_xor(mx, off));
                const float mnew = fmaxf(mold, mx);
                const float alpha = exp2f(mold - mnew);
                mold = mnew;
                #pragma unroll
                for (int m = 0; m < 2; ++m) {
                    short* pp = &sP[buf][u][mh * 32 + m * 16 + quad * 4][mi];
                    #pragma unroll
                    for (int r = 0; r < 4; ++r) {
                        const float pa = exp2f(S[m][0][r] - mnew);
                        const float pb = exp2f(S[m][1][r] - mnew);
                        lsum[m][r] = lsum[m][r] * alpha + (pa + pb);
                        pp[r * 40]      = f2bf(pa);
                        pp[r * 40 + 16] = f2bf(pb);
                    }
                }
                if (lane == 0) sAl[buf][u][mh] = alpha;
            } else {
                if (t > 0) {
                    // ---- PV(t-1) ----
                    const int pbuf = (t - 1) & 1;
                    const float a00 = sAl[pbuf][0][0], a01 = sAl[pbuf][0][1];
                    const float a10 = sAl[pbuf][1][0], a11 = sAl[pbuf][1][1];
                    if (a00 != 1.f || a01 != 1.f || a10 != 1.f || a11 != 1.f) {
                        #pragma unroll
                        for (int m = 0; m < 4; ++m) {
                            const float aa0 = (m < 2) ? a00 : a01;
                            const float aa1 = (m < 2) ? a10 : a11;
                            #pragma unroll
                            for (int nb = 0; nb < 4; ++nb)
                                #pragma unroll
                                for (int r = 0; r < 4; ++r) {
                                    O[0][m][nb][r] *= aa0;
                                    O[1][m][nb][r] *= aa1;
                                }
                        }
                    }
                    short8 pA[2][4];
                    #pragma unroll
                    for (int a = 0; a < 2; ++a)
                        #pragma unroll
                        for (int m = 0; m < 4; ++m)
                            pA[a][m] = *(const short8*)&sP[pbuf][a][m * 16 + mi][quad * 8];
                    short8 bv[4];
                    #pragma unroll
                    for (int nb = 0; nb < 4; ++nb)
                        bv[nb] = *(const short8*)&sV[pbuf][quad * 2048 + (nq * 64 + nb * 16 + mi) * 8];
                    #pragma unroll
                    for (int nb = 0; nb < 4; ++nb)
                        #pragma unroll
                        for (int a = 0; a < 2; ++a)
                            #pragma unroll
                            for (int m = 0; m < 4; ++m)
                                O[a][m][nb] = __builtin_amdgcn_mfma_f32_16x16x32_bf16(pA[a][m], bv[nb], O[a][m][nb], 0, 0, 0);
                    // prefetch V(t+1) into sV[buf^1] (own slice; own reads done)
                    if (t + 1 < nt) {
                        const short* src = vtile0 + ((size_t)(t + 1) << 13) + nq * 512 + lane * 8;
                        short* dst = &sV[buf ^ 1][nq * 512 + lane * 8];
                        #pragma unroll
                        for (int kc = 0; kc < 4; ++kc) async16(src + kc * 2048, dst + kc * 2048);
                    }
                } else {
                    // prefetch V(1)
                    const short* src = vtile0 + ((size_t)1 << 13) + nq * 512 + lane * 8;
                    short* dst = &sV[1][nq * 512 + lane * 8];
                    #pragma unroll
                    for (int kc = 0; kc < 4; ++kc) async16(src + kc * 2048, dst + kc * 2048);
                }
            }
            __syncthreads();
        }

        // ---- drain PV(nt-1); QK reduces l ----
        if (isQK) {
            #pragma unroll
            for (int m = 0; m < 2; ++m)
                #pragma unroll
                for (int r = 0; r < 4; ++r) {
                    float s = lsum[m][r];
                    s += __shfl_xor(s, 1); s += __shfl_xor(s, 2);
                    s += __shfl_xor(s, 4); s += __shfl_xor(s, 8);
                    if (mi == 0) sL[u][mh * 32 + m * 16 + quad * 4 + r] = s;
                }
        } else {
            const int pbuf = (nt - 1) & 1;
            const float a00 = sAl[pbuf][0][0], a01 = sAl[pbuf][0][1];
            const float a10 = sAl[pbuf][1][0], a11 = sAl[pbuf][1][1];
            if (a00 != 1.f || a01 != 1.f || a10 != 1.f || a11 != 1.f) {
                #pragma unroll
                for (int m = 0; m < 4; ++m) {
                    const float aa0 = (m < 2) ? a00 : a01;
                    const float aa1 = (m < 2) ? a10 : a11;
                    #pragma unroll
                    for (int nb = 0; nb < 4; ++nb)
                        #pragma unroll
                        for (int r = 0; r < 4; ++r) {
                            O[0][m][nb][r] *= aa0;
                            O[1][m][nb][r] *= aa1;
                        }
                }
            }
            short8 pA[2][4];
            #pragma unroll
            for (int a = 0; a < 2; ++a)
                #pragma unroll
                for (int m = 0; m < 4; ++m)
                    pA[a][m] = *(const short8*)&sP[pbuf][a][m * 16 + mi][quad * 8];
            short8 bv[4];
            #pragma unroll
            for (int nb = 0; nb < 4; ++nb)
                bv[nb] = *(const short8*)&sV[pbuf][quad * 2048 + (nq * 64 + nb * 16 + mi) * 8];
            #pragma unroll
            for (int nb = 0; nb < 4; ++nb)
                #pragma unroll
                for (int a = 0; a < 2; ++a)
                    #pragma unroll
                    for (int m = 0; m < 4; ++m)
                        O[a][m][nb] = __builtin_amdgcn_mfma_f32_16x16x32_bf16(pA[a][m], bv[nb], O[a][m][nb], 0, 0, 0);
        }
        __syncthreads();

        // ---- epilogue (PV waves): combine + RMS partials ----
        float ss[4][4];
        if (!isQK) {
            #pragma unroll
            for (int m = 0; m < 4; ++m)
                #pragma unroll
                for (int r = 0; r < 4; ++r) {
                    const int row = m * 16 + quad * 4 + r;
                    const float il1 = 1.0f / sL[0][row];
                    const float il2 = lambda_full / sL[1][row];
                    float acc = 0.f;
                    #pragma unroll
                    for (int nb = 0; nb < 4; ++nb) {
                        const float c = O[0][m][nb][r] * il1 - O[1][m][nb][r] * il2;
                        O[0][m][nb][r] = c;
                        acc += c * c;
                    }
                    acc += __shfl_xor(acc, 1); acc += __shfl_xor(acc, 2);
                    acc += __shfl_xor(acc, 4); acc += __shfl_xor(acc, 8);
                    ss[m][r] = acc;
                    if (mi == 0) sRed[nq][row] = acc;
                }
        }
        __syncthreads();

        if (!isQK) {
            #pragma unroll
            for (int m = 0; m < 4; ++m)
                #pragma unroll
                for (int r = 0; r < 4; ++r) {
                    const int row = m * 16 + quad * 4 + r;
                    const float tot = sRed[0][row] + sRed[1][row] + sRed[2][row] + sRed[3][row];
                    const float scale = rsqrtf(tot * (1.0f / 256.0f) + 1e-5f) * (1.0f - LAMBDA_INIT);
                    float* ob = out + ((size_t)(b * S_LEN + qbase + row)) * ROWSTR + h * 256 + nq * 64 + mi;
                    #pragma unroll
                    for (int nb = 0; nb < 4; ++nb)
                        ob[nb * 16] = O[0][m][nb][r] * scale;
                }
        }
        __syncthreads();   // protect sL/sRed/sP/sK/sV before next phase
    }
}

extern "C" void kernel_launch(void* const* d_in, const int* in_sizes, int n_in,
                              void* d_out, int out_size, void* d_ws, size_t ws_size,
                              hipStream_t stream) {
    (void)in_sizes; (void)n_in; (void)out_size; (void)ws_size;
    const float* q   = (const float*)d_in[0];
    const float* k   = (const float*)d_in[1];
    const float* v   = (const float*)d_in[2];
    const float* lq1 = (const float*)d_in[3];
    const float* lk1 = (const float*)d_in[4];
    const float* lq2 = (const float*)d_in[5];
    const float* lk2 = (const float*)d_in[6];
    float* out = (float*)d_out;

    short* kws = (short*)d_ws;                  // 16 bh x 64 t x 8192 shorts
    short* vws = kws + (size_t)16 * 64 * 8192;  // total 67 MB

    prep_kernel<<<dim3(1024), dim3(256), 0, stream>>>(k, v, kws, vws);
    // 256 blocks = 16 bh x 16 pairs (qt = 31-g then g): 66 tiles each, 1/CU
    fda_kernel<<<dim3(256), dim3(512), 0, stream>>>(kws, vws, q,
                                                    lq1, lk1, lq2, lk2, out);
}